// Round 5
// baseline (109.326 us; speedup 1.0000x reference)
//
#include <hip/hip_runtime.h>
#include <hip/hip_bf16.h>

#define S_TOT 4096
#define NA 64
#define DIN 128
#define HD 128   // H*D
#define NH 4
#define DH 32
#define QROWS 16
#define KSPLIT 2
#define KT_PER_WAVE 4   // 8 waves * KSPLIT * KT_PER_WAVE * 64 keys = 4096
// (1/sqrt(32)) * log2(e): fold softmax scale + base-2 conversion into Q
#define QSC 0.2550348564632784f

typedef __attribute__((ext_vector_type(8))) short bf16x8;
typedef __attribute__((ext_vector_type(4))) short bf16x4;
typedef __attribute__((ext_vector_type(4))) float f32x4;

#define EXP2(x) exp2f(x)

#define MFMA32(A, B, C) __builtin_amdgcn_mfma_f32_16x16x32_bf16(A, B, C, 0, 0, 0)
// K=16 bf16 MFMA: gfx9xx builtin spelling is the _1k variant (4xbf16 frags).
// NOTE: do NOT guard with __has_builtin -- it returns false in the HIP host
// pass for aux-target builtins even though they are declared there.
#define MFMA16(A, B, C) __builtin_amdgcn_mfma_f32_16x16x16bf16_1k(A, B, C, 0, 0, 0)

// pack two fp32 -> bf16x2 dword (truncating; used only for P>=0 numerators)
__device__ __forceinline__ unsigned pk_bf16(float lo, float hi) {
    return __builtin_amdgcn_perm(__builtin_bit_cast(unsigned, hi),
                                 __builtin_bit_cast(unsigned, lo), 0x07060302u);
}

// ---------------- Kernel W: transpose+cvt W -> Wt[w][n][k] bf16 ------------
// grid (3, 8) x 256 thr. Coalesced fp32 reads, LDS transpose, 96 KB out.
__global__ __launch_bounds__(256) void wt_kernel(
    const float* __restrict__ Wq, const float* __restrict__ Wk,
    const float* __restrict__ Wv, unsigned short* __restrict__ Wt)
{
    __shared__ unsigned short tile[16][DIN + 8];
    const int w  = blockIdx.x;        // 0=Q 1=K 2=V
    const int k0 = blockIdx.y * 16;   // k strip
    const float* W = (w == 0) ? Wq : (w == 1 ? Wk : Wv);
    const int tid = threadIdx.x;
    #pragma unroll
    for (int j = 0; j < 8; ++j) {
        const int idx = tid + j * 256;            // 0..2047 = 16k x 128n
        const int kl = idx >> 7, n = idx & 127;
        tile[kl][n] = __builtin_bit_cast(unsigned short,
            __float2bfloat16(W[(size_t)(k0 + kl) * HD + n]));
    }
    __syncthreads();
    #pragma unroll
    for (int j = 0; j < 8; ++j) {
        const int idx = tid + j * 256;
        const int n = idx >> 4, kl = idx & 15;
        Wt[(size_t)w * HD * DIN + (size_t)n * DIN + k0 + kl] = tile[kl][n];
    }
}

// ---------------- Kernel A: MFMA QKV projection -> bf16 Qb/Kb/Vt -----------
// grid 256 x 512 thr (8 waves). Block owns 16 rows of X; wave owns 3 of the
// 24 (Q|K|V) 16-col n-tiles. B-frags = contiguous 16 B loads from Wt.
__global__ __launch_bounds__(512) void qkv_kernel(
    const float* __restrict__ x, const unsigned short* __restrict__ Wt,
    const float* __restrict__ bq, const float* __restrict__ bk,
    const float* __restrict__ bv,
    __hip_bfloat16* __restrict__ Qb, __hip_bfloat16* __restrict__ Kb,
    __hip_bfloat16* __restrict__ Vt)
{
    __shared__ __hip_bfloat16 xs[QROWS][DIN + 8];
    const int tid = threadIdx.x;
    const int c  = tid & 15;
    const int g  = (tid >> 4) & 3;
    const int wv = tid >> 6;
    const int r0 = blockIdx.x * QROWS;

    {   // stage 16x128 fp32 -> bf16 (RNE): 4 elements per thread
        const int e  = tid * 4;
        const int rr = e >> 7, cc = e & 127;
        const float4 xv = *(const float4*)(x + (size_t)(r0 + rr) * DIN + cc);
        xs[rr][cc + 0] = __float2bfloat16(xv.x);
        xs[rr][cc + 1] = __float2bfloat16(xv.y);
        xs[rr][cc + 2] = __float2bfloat16(xv.z);
        xs[rr][cc + 3] = __float2bfloat16(xv.w);
    }
    __syncthreads();

    // A-frags: lane (c,g) holds X[r0+c][ks*32 + g*8 .. +7]
    bf16x8 af[4];
    #pragma unroll
    for (int ks = 0; ks < 4; ++ks)
        af[ks] = *(const bf16x8*)&xs[c][ks * 32 + g * 8];

    #pragma unroll
    for (int t = 0; t < 3; ++t) {
        const int nt = wv * 3 + t;                 // 0..23: Q 0-7, K 8-15, V 16-23
        const int widx = (nt < 8) ? 0 : (nt < 16 ? 1 : 2);
        const float* bb = (nt < 8) ? bq : (nt < 16 ? bk : bv);
        const int n0 = (nt & 7) * 16;
        const unsigned short* Wtw = Wt + (size_t)widx * HD * DIN;

        f32x4 acc = {0.f, 0.f, 0.f, 0.f};
        #pragma unroll
        for (int ks = 0; ks < 4; ++ks) {
            // B-frag: lane (c,g) holds W[ks*32+g*8+j][n0+c] = Wt[n0+c][k...]
            const bf16x8 bfv = *(const bf16x8*)(Wtw + (size_t)(n0 + c) * DIN + ks * 32 + g * 8);
            acc = MFMA32(af[ks], bfv, acc);
        }
        // C-layout: row = g*4+r, col = n0+c
        const float bval = bb[n0 + c];
        if (nt < 8) {
            #pragma unroll
            for (int r = 0; r < 4; ++r)
                Qb[(size_t)(r0 + g * 4 + r) * HD + n0 + c] =
                    __float2bfloat16((acc[r] + bval) * QSC);
        } else if (nt < 16) {
            #pragma unroll
            for (int r = 0; r < 4; ++r)
                Kb[(size_t)(r0 + g * 4 + r) * HD + n0 + c] =
                    __float2bfloat16(acc[r] + bval);
        } else {
            // Vt[n0+c][r0+g*4 .. +3]: contiguous 4 bf16 = 8 B store
            unsigned short p[4];
            #pragma unroll
            for (int r = 0; r < 4; ++r)
                p[r] = __builtin_bit_cast(unsigned short,
                        __float2bfloat16(acc[r] + bval));
            uint2 d;
            d.x = ((unsigned)p[1] << 16) | p[0];
            d.y = ((unsigned)p[3] << 16) | p[2];
            *(uint2*)((unsigned short*)Vt + (size_t)(n0 + c) * S_TOT + r0 + g * 4) = d;
        }
    }
}

// ---------------- Kernel B: MFMA flash attention (key-split) ---------------
// grid (64, 4, KSPLIT) x 512 thr. Wave owns 256 keys (4 tiles of 64).
// Writes UNNORMALIZED O-partials + L-partials to ws; merge_kernel finishes.
__global__ __launch_bounds__(512) void attn_kernel(
    const __hip_bfloat16* __restrict__ Qbp, const __hip_bfloat16* __restrict__ Kbp,
    const __hip_bfloat16* __restrict__ Vtp, const int* __restrict__ am,
    float* __restrict__ Op, float* __restrict__ Lp)
{
    __shared__ float pO[8][64][33];   // per-wave unnormalized O^T partials
    __shared__ float pL[8][64];       // per-wave softmax-denominator partials
    __shared__ float amadd[64];
    __shared__ int allvS;

    const int i   = blockIdx.x;
    const int h   = blockIdx.y;
    const int z   = blockIdx.z;
    const int tid = threadIdx.x;
    const int c   = tid & 15;
    const int g   = (tid >> 4) & 3;
    const int wv  = tid >> 6;

    if (tid < 64) {
        const int a = am[tid];
        amadd[tid] = a ? 0.f : -1e30f;
        const unsigned long long bal = __ballot(a != 0);
        if (tid == 0) allvS = (bal == ~0ull) ? 1 : 0;
    }
    __syncthreads();
    const bool allv = (allvS != 0);

    const short* Q = (const short*)Qbp;
    const short* K = (const short*)Kbp;
    const short* V = (const short*)Vtp;

    bf16x8 qf[4];
    #pragma unroll
    for (int qs = 0; qs < 4; ++qs)
        qf[qs] = *(const bf16x8*)(Q + ((size_t)(i * 64 + qs * 16 + c) * HD + h * DH + g * 8));

    f32x4 acc[2][4];
    #pragma unroll
    for (int ds = 0; ds < 2; ++ds)
        #pragma unroll
        for (int qs = 0; qs < 4; ++qs)
            acc[ds][qs] = (f32x4){0.f, 0.f, 0.f, 0.f};
    float l_run[4] = {0.f, 0.f, 0.f, 0.f};

    const int t0base = z * (S_TOT / KSPLIT) + wv * (KT_PER_WAVE * 64);
    bf16x8 ka[4];
    #pragma unroll
    for (int ms = 0; ms < 4; ++ms)
        ka[ms] = *(const bf16x8*)(K + ((size_t)(t0base + ms * 16 + c) * HD + h * DH + g * 8));

    for (int kt = 0; kt < KT_PER_WAVE; ++kt) {
        const int t0 = t0base + kt * 64;

        bf16x4 va[2][4];
        #pragma unroll
        for (int ds = 0; ds < 2; ++ds)
            #pragma unroll
            for (int ks = 0; ks < 4; ++ks)
                va[ds][ks] = *(const bf16x4*)(V + ((size_t)(h * DH + ds * 16 + c) * S_TOT + t0 + ks * 16 + g * 4));

        f32x4 sc[4][4];
        #pragma unroll
        for (int ms = 0; ms < 4; ++ms)
            #pragma unroll
            for (int qs = 0; qs < 4; ++qs)
                sc[ms][qs] = MFMA32(ka[ms], qf[qs], ((f32x4){0.f, 0.f, 0.f, 0.f}));

        bf16x8 kan[4];
        if (kt < KT_PER_WAVE - 1) {
            #pragma unroll
            for (int ms = 0; ms < 4; ++ms)
                kan[ms] = *(const bf16x8*)(K + ((size_t)(t0 + 64 + ms * 16 + c) * HD + h * DH + g * 8));
        }

        if (!allv) {
            const float tadd = am[t0 >> 6] ? 0.f : -1e30f;
            #pragma unroll
            for (int ms = 0; ms < 4; ++ms)
                #pragma unroll
                for (int r = 0; r < 4; ++r) {
                    const float a = amadd[ms * 16 + g * 4 + r] + tadd;
                    #pragma unroll
                    for (int qs = 0; qs < 4; ++qs) sc[ms][qs][r] += a;
                }
        }

        unsigned pk[4][4][2];
        #pragma unroll
        for (int qs = 0; qs < 4; ++qs) {
            float rs = 0.f;
            #pragma unroll
            for (int ms = 0; ms < 4; ++ms) {
                const float p0 = EXP2(sc[ms][qs][0]);
                const float p1 = EXP2(sc[ms][qs][1]);
                const float p2 = EXP2(sc[ms][qs][2]);
                const float p3 = EXP2(sc[ms][qs][3]);
                rs += (p0 + p1) + (p2 + p3);
                pk[ms][qs][0] = pk_bf16(p0, p1);
                pk[ms][qs][1] = pk_bf16(p2, p3);
            }
            rs += __shfl_xor(rs, 16);
            rs += __shfl_xor(rs, 32);
            l_run[qs] += rs;
        }

        #pragma unroll
        for (int ks = 0; ks < 4; ++ks)
            #pragma unroll
            for (int qs = 0; qs < 4; ++qs) {
                union { unsigned u[2]; bf16x4 v; } bb;
                bb.u[0] = pk[ks][qs][0];
                bb.u[1] = pk[ks][qs][1];
                #pragma unroll
                for (int ds = 0; ds < 2; ++ds)
                    acc[ds][qs] = MFMA16(va[ds][ks], bb.v, acc[ds][qs]);
            }

        #pragma unroll
        for (int ms = 0; ms < 4; ++ms) ka[ms] = kan[ms];
    }

    // ---- epilogue: merge 8 wave-partials -> unnormalized ws partials
    #pragma unroll
    for (int ds = 0; ds < 2; ++ds)
        #pragma unroll
        for (int qs = 0; qs < 4; ++qs)
            #pragma unroll
            for (int r = 0; r < 4; ++r)
                pO[wv][qs * 16 + c][ds * 16 + g * 4 + r] = acc[ds][qs][r];
    if (g == 0) {
        #pragma unroll
        for (int qs = 0; qs < 4; ++qs) pL[wv][qs * 16 + c] = l_run[qs];
    }
    __syncthreads();

    const int p = (i * NH + h) * KSPLIT + z;
    {
        const int d = tid & 31;
        const int q0 = (tid >> 5) * 4;   // 16 groups x 4 q = 64 q
        #pragma unroll
        for (int qq = 0; qq < 4; ++qq) {
            const int q = q0 + qq;
            float o = 0.f;
            #pragma unroll
            for (int w = 0; w < 8; ++w) o += pO[w][q][d];
            Op[(size_t)p * (64 * DH) + q * DH + d] = o;
        }
    }
    if (tid < 64) {
        float L = 0.f;
        #pragma unroll
        for (int w = 0; w < 8; ++w) L += pL[w][tid];
        Lp[(size_t)p * 64 + tid] = L;
    }
}

// ---------------- Kernel C: merge splits, normalize, sum-pool --------------
// grid (64, 4) x 128 thr.
__global__ __launch_bounds__(128) void merge_kernel(
    const float* __restrict__ Op, const float* __restrict__ Lp,
    float* __restrict__ out)
{
    __shared__ float rinv[64];
    __shared__ float red[4][33];
    const int i = blockIdx.x, h = blockIdx.y;
    const int tid = threadIdx.x;
    const int p0 = (i * NH + h) * KSPLIT;

    if (tid < 64) {
        float L = 0.f;
        #pragma unroll
        for (int zz = 0; zz < KSPLIT; ++zz) L += Lp[(size_t)(p0 + zz) * 64 + tid];
        rinv[tid] = 1.f / fmaxf(L, 1e-30f);
    }
    __syncthreads();

    const int d = tid & 31, qg = tid >> 5;   // 4 groups of 16 q
    float s = 0.f;
    #pragma unroll 4
    for (int qq = 0; qq < 16; ++qq) {
        const int q = qg * 16 + qq;
        float o = 0.f;
        #pragma unroll
        for (int zz = 0; zz < KSPLIT; ++zz)
            o += Op[(size_t)(p0 + zz) * (64 * DH) + q * DH + d];
        s += o * rinv[q];
    }
    red[qg][d] = s;
    __syncthreads();

    if (tid < 32)
        out[(size_t)i * HD + h * DH + tid] =
            (red[0][tid] + red[1][tid]) + (red[2][tid] + red[3][tid]);
}

extern "C" void kernel_launch(void* const* d_in, const int* in_sizes, int n_in,
                              void* d_out, int out_size, void* d_ws, size_t ws_size,
                              hipStream_t stream) {
    const float* x  = (const float*)d_in[0];
    const int*   am = (const int*)d_in[1];
    const float* bq = (const float*)d_in[3];
    const float* bk = (const float*)d_in[5];
    const float* bv = (const float*)d_in[7];
    const float* Wq = (const float*)d_in[2];
    const float* Wk = (const float*)d_in[4];
    const float* Wv = (const float*)d_in[6];
    float* outp = (float*)d_out;

    char* ws = (char*)d_ws;
    __hip_bfloat16* Qb = (__hip_bfloat16*)(ws + 0);               // 1 MB
    __hip_bfloat16* Kb = (__hip_bfloat16*)(ws + (1u << 20));      // 1 MB
    __hip_bfloat16* Vt = (__hip_bfloat16*)(ws + (2u << 20));      // 1 MB, [128][4096]
    unsigned short* Wt = (unsigned short*)(ws + (3u << 20));      // 96 KB, [3][128][128]
    float* Op = (float*)(ws + (4u << 20));   // [64*4*KSPLIT][64][32] = 4.2 MB
    float* Lp = (float*)(ws + (9u << 20));   // [64*4*KSPLIT][64]    = 131 KB

    wt_kernel<<<dim3(3, 8), 256, 0, stream>>>(Wq, Wk, Wv, Wt);
    qkv_kernel<<<S_TOT / QROWS, 512, 0, stream>>>(x, Wt, bq, bk, bv, Qb, Kb, Vt);
    attn_kernel<<<dim3(NA, NH, KSPLIT), 512, 0, stream>>>(Qb, Kb, Vt, am, Op, Lp);
    merge_kernel<<<dim3(NA, NH), 128, 0, stream>>>(Op, Lp, outp);
}